// Round 5
// baseline (433.815 us; speedup 1.0000x reference)
//
#include <hip/hip_runtime.h>
#include <hip/hip_bf16.h>

typedef __attribute__((ext_vector_type(8))) short short8;
typedef __attribute__((ext_vector_type(4))) float f32x4;

#define MFMA_B16(a, b, c) __builtin_amdgcn_mfma_f32_16x16x32_bf16((a), (b), (c), 0, 0, 0)

__device__ __forceinline__ float bf2f(unsigned short u) {
    union { unsigned int i; float f; } v; v.i = ((unsigned int)u) << 16; return v.f;
}
__device__ __forceinline__ unsigned short f2bf(float f) {
    union { float f; unsigned int i; } v; v.f = f;
    unsigned int r = v.i + 0x7fffu + ((v.i >> 16) & 1u);
    return (unsigned short)(r >> 16);
}
__device__ __forceinline__ float sigm(float x) {
    return __frcp_rn(1.0f + __expf(-x));
}
__device__ __forceinline__ float tanh_fast(float x) {
    return 1.0f - 2.0f * __frcp_rn(__expf(2.0f * x) + 1.0f);
}

// probe 256 shorts: count bf16-plausible exponent fields. fp32-as-shorts ~138,
// bf16 ~256. threshold 200 discriminates. Deterministic per call.
__device__ __forceinline__ bool probe_bf16(const unsigned short* p, int tid, int* s_cnt) {
    if (tid == 0) *s_cnt = 0;
    __syncthreads();
    unsigned short s = p[tid & 255];
    int e = (s >> 7) & 0xFF;
    if (tid < 256 && e >= 117 && e <= 137) atomicAdd(s_cnt, 1);
    __syncthreads();
    return *s_cnt >= 200;
}

// ---------------------------------------------------------------------------
// Convert the 22 weight/bias/h0 tensors (everything except x) to a bf16 arena.
// ---------------------------------------------------------------------------
struct WArgs {
    const void* src[22];
    int off[23];   // arena element offsets (prefix); off[22] = total
};

__global__ __launch_bounds__(256)
void convert_w(WArgs a, unsigned short* __restrict__ arena,
               const unsigned short* __restrict__ probe)
{
    __shared__ int cnt;
    const bool bf = probe_bf16(probe, threadIdx.x, &cnt);
    const int total = a.off[22];
    for (int i = blockIdx.x * 256 + threadIdx.x; i < total; i += gridDim.x * 256) {
        int t = 0;
        while (t < 21 && i >= a.off[t + 1]) ++t;
        const int local = i - a.off[t];
        arena[i] = bf ? ((const unsigned short*)a.src[t])[local]
                      : f2bf(((const float*)a.src[t])[local]);
    }
}

// ---------------------------------------------------------------------------
// Layer 1: bidirectional GRU(64), relu candidate. Reads x directly from d_in
// (dtype probed per block; fp32 split into hi/lo bf16 inline). Writes a seq
// CHUNK (T, bchunk, 128) bf16 [fwd 0:64, bwd 64:128].
// grid: (bchunk/32, 2), block 256.
// ---------------------------------------------------------------------------
__global__ __launch_bounds__(256, 1)
void gru1_kernel(const void* __restrict__ X, int cb, int bchunk,
                 const unsigned short* __restrict__ h0f,
                 const unsigned short* __restrict__ h0b,
                 const unsigned short* __restrict__ Wf, const unsigned short* __restrict__ Uf,
                 const unsigned short* __restrict__ bif, const unsigned short* __restrict__ brf,
                 const unsigned short* __restrict__ Wb, const unsigned short* __restrict__ Ub,
                 const unsigned short* __restrict__ bib, const unsigned short* __restrict__ brb,
                 unsigned short* __restrict__ seq)
{
    const int tid  = threadIdx.x;
    const int lane = tid & 63;
    const int wv   = tid >> 6;
    const int q    = lane >> 4;
    const int ln   = lane & 15;
    const int dir  = blockIdx.y;
    const int lb0  = blockIdx.x * 32;        // local row base within chunk
    const int gb0  = cb + lb0;               // global batch row base
    const int u    = wv * 16 + ln;

    const unsigned short* W  = dir ? Wb  : Wf;
    const unsigned short* U  = dir ? Ub  : Uf;
    const unsigned short* bi = dir ? bib : bif;
    const unsigned short* br = dir ? brb : brf;
    const unsigned short* h0 = dir ? h0b : h0f;

    __shared__ __align__(16) unsigned short Ah[2][32][136];
    __shared__ __align__(16) unsigned short Ax[2][32][40];   // 18 real (hi/lo), rest 0
    __shared__ __align__(16) unsigned short stg[2][32][64];
    __shared__ int s_cnt;

    const bool xbf = probe_bf16((const unsigned short*)X, tid, &s_cnt);

    // zero both Ax buffers (cols >=18 must stay 0 forever)
    {
        unsigned short* p = &Ax[0][0][0];
        for (int i = tid; i < 2 * 32 * 40; i += 256) p[i] = 0;
    }
    __syncthreads();

    // load x(t=0): 32 rows x 9 feats -> hi/lo pairs
    {
        const int tx0 = dir ? 71 : 0;
        for (int i = tid; i < 288; i += 256) {
            int r = i / 9, k = i - 9 * r;
            size_t idx = ((size_t)(gb0 + r) * 72 + tx0) * 9 + k;
            unsigned short hv, lv;
            if (xbf) { hv = ((const unsigned short*)X)[idx]; lv = 0; }
            else { float v = ((const float*)X)[idx]; hv = f2bf(v); lv = f2bf(v - bf2f(hv)); }
            Ax[0][r][2 * k]     = hv;
            Ax[0][r][2 * k + 1] = lv;
        }
    }

    // B-fragments: lane holds B[k=q*8+j][n=ln] of its wave's 16-col tile
    short8 bU[3][4];   // recurrent, K=128 hi/lo interleaved: U row = kp>>1
    short8 bW[3];      // x projection, K=32 (18 real hi/lo): W row = kp>>1
#pragma unroll
    for (int g = 0; g < 3; ++g) {
        const int col = g * 64 + u;
#pragma unroll
        for (int ks = 0; ks < 4; ++ks) {
            short8 f;
#pragma unroll
            for (int j = 0; j < 8; ++j) {
                int kp = ks * 32 + q * 8 + j;
                f[j] = (short)U[(size_t)(kp >> 1) * 192 + col];
            }
            bU[g][ks] = f;
        }
        short8 fw;
#pragma unroll
        for (int j = 0; j < 8; ++j) {
            int kp = q * 8 + j;
            fw[j] = (kp < 18) ? (short)W[(size_t)(kp >> 1) * 192 + col] : (short)0;
        }
        bW[g] = fw;
    }

    const float bz  = bf2f(bi[u])       + bf2f(br[u]);
    const float brg = bf2f(bi[64 + u])  + bf2f(br[64 + u]);
    const float bih = bf2f(bi[128 + u]);
    const float brh = bf2f(br[128 + u]);

    float hreg[2][4];
#pragma unroll
    for (int rt = 0; rt < 2; ++rt) {
#pragma unroll
        for (int i = 0; i < 4; ++i) {
            int m = rt * 16 + q * 4 + i;
            float hv = bf2f(h0[(size_t)(gb0 + m) * 64 + u]);
            hreg[rt][i] = hv;
            unsigned short hi = f2bf(hv);
            unsigned short lo = f2bf(hv - bf2f(hi));
            *(unsigned int*)&Ah[0][m][2 * u] = (unsigned int)hi | ((unsigned int)lo << 16);
        }
    }
    __syncthreads();

    const int r2 = tid >> 3, c2 = tid & 7;
    const f32x4 Z4 = {0.f, 0.f, 0.f, 0.f};

    for (int t = 0; t < 72; ++t) {
        const int cur = t & 1, nb = cur ^ 1;

        // prefetch x(t+1): 288 feats -> hi/lo in registers
        unsigned short h0v = 0, l0v = 0, h1v = 0, l1v = 0;
        int r0x = 0, k0x = 0, r1x = 0, k1x = 0;
        if (t < 71) {
            const int tx = dir ? (70 - t) : (t + 1);
            r0x = tid / 9; k0x = tid - 9 * r0x;           // i = tid < 256
            if (tid < 256) {
                size_t idx = ((size_t)(gb0 + r0x) * 72 + tx) * 9 + k0x;
                if (xbf) { h0v = ((const unsigned short*)X)[idx]; l0v = 0; }
                else { float v = ((const float*)X)[idx]; h0v = f2bf(v); l0v = f2bf(v - bf2f(h0v)); }
            }
            if (tid < 32) {
                int i1 = 256 + tid; r1x = i1 / 9; k1x = i1 - 9 * r1x;
                size_t idx = ((size_t)(gb0 + r1x) * 72 + tx) * 9 + k1x;
                if (xbf) { h1v = ((const unsigned short*)X)[idx]; l1v = 0; }
                else { float v = ((const float*)X)[idx]; h1v = f2bf(v); l1v = f2bf(v - bf2f(h1v)); }
            }
        }

        // flush previous step's h to seq (chunk-local indexing)
        if (t > 0) {
            const int tw = dir ? (71 - (t - 1)) : (t - 1);
            int4 v = *(const int4*)&stg[nb][r2][c2 * 8];
            *(int4*)(seq + ((size_t)tw * bchunk + lb0 + r2) * 128 + dir * 64 + c2 * 8) = v;
        }

        // MFMA phase
        f32x4 acz[2], acr[2], ach[2], axz[2], axr[2], axh[2];
#pragma unroll
        for (int rt = 0; rt < 2; ++rt) {
            const unsigned short* ap = &Ah[cur][rt * 16 + ln][0];
            short8 a0 = *(const short8*)(ap + q * 8);
            acz[rt] = MFMA_B16(a0, bU[0][0], Z4);
            acr[rt] = MFMA_B16(a0, bU[1][0], Z4);
            ach[rt] = MFMA_B16(a0, bU[2][0], Z4);
#pragma unroll
            for (int ks = 1; ks < 4; ++ks) {
                short8 a = *(const short8*)(ap + ks * 32 + q * 8);
                acz[rt] = MFMA_B16(a, bU[0][ks], acz[rt]);
                acr[rt] = MFMA_B16(a, bU[1][ks], acr[rt]);
                ach[rt] = MFMA_B16(a, bU[2][ks], ach[rt]);
            }
            short8 ax = *(const short8*)(&Ax[cur][rt * 16 + ln][q * 8]);
            axz[rt] = MFMA_B16(ax, bW[0], Z4);
            axr[rt] = MFMA_B16(ax, bW[1], Z4);
            axh[rt] = MFMA_B16(ax, bW[2], Z4);
        }

        // gates + state update
#pragma unroll
        for (int rt = 0; rt < 2; ++rt) {
#pragma unroll
            for (int i = 0; i < 4; ++i) {
                const int m = rt * 16 + q * 4 + i;
                float z = sigm(acz[rt][i] + axz[rt][i] + bz);
                float r = sigm(acr[rt][i] + axr[rt][i] + brg);
                float pre = axh[rt][i] + bih + r * (ach[rt][i] + brh);
                float hh = fmaxf(pre, 0.0f);
                float hn = z * hreg[rt][i] + (1.0f - z) * hh;
                hreg[rt][i] = hn;
                unsigned short hi = f2bf(hn);
                unsigned short lo = f2bf(hn - bf2f(hi));
                *(unsigned int*)&Ah[nb][m][2 * u] = (unsigned int)hi | ((unsigned int)lo << 16);
                stg[cur][m][u] = hi;
            }
        }

        if (t < 71) {
            if (tid < 256) { Ax[nb][r0x][2 * k0x] = h0v; Ax[nb][r0x][2 * k0x + 1] = l0v; }
            if (tid < 32)  { Ax[nb][r1x][2 * k1x] = h1v; Ax[nb][r1x][2 * k1x + 1] = l1v; }
        }
        __syncthreads();
    }

    {
        const int tw = dir ? 0 : 71;
        int4 v = *(const int4*)&stg[1][r2][c2 * 8];
        *(int4*)(seq + ((size_t)tw * bchunk + lb0 + r2) * 128 + dir * 64 + c2 * 8) = v;
    }
}

// ---------------------------------------------------------------------------
// Layer 2: bidirectional GRU(64), tanh, input = seq chunk (T,bchunk,128),
// zero init state, fused input projection, final states -> feat (B,128) fp32
// ---------------------------------------------------------------------------
__global__ __launch_bounds__(256, 1)
void gru2_kernel(const unsigned short* __restrict__ seq, int cb, int bchunk,
                 const unsigned short* __restrict__ W2f, const unsigned short* __restrict__ U2f,
                 const unsigned short* __restrict__ bi2f, const unsigned short* __restrict__ br2f,
                 const unsigned short* __restrict__ W2b, const unsigned short* __restrict__ U2b,
                 const unsigned short* __restrict__ bi2b, const unsigned short* __restrict__ br2b,
                 float* __restrict__ feat)
{
    const int tid  = threadIdx.x;
    const int lane = tid & 63;
    const int wv   = tid >> 6;
    const int q    = lane >> 4;
    const int ln   = lane & 15;
    const int dir  = blockIdx.y;
    const int lb0  = blockIdx.x * 32;
    const int gb0  = cb + lb0;
    const int u    = wv * 16 + ln;

    const unsigned short* W  = dir ? W2b  : W2f;
    const unsigned short* U  = dir ? U2b  : U2f;
    const unsigned short* bi = dir ? bi2b : bi2f;
    const unsigned short* br = dir ? br2b : br2f;

    __shared__ __align__(16) unsigned short Ah[2][32][136];
    __shared__ __align__(16) unsigned short As[2][32][136];

    {
        unsigned short* p = &Ah[0][0][0];
        for (int i = tid; i < 32 * 136; i += 256) p[i] = 0;
    }

    const int r2 = tid >> 3, c2 = tid & 7;
    {
        const int tx0 = dir ? 71 : 0;
        size_t base = ((size_t)tx0 * bchunk + lb0 + r2) * 128 + c2 * 16;
        *(int4*)&As[0][r2][c2 * 16]     = *(const int4*)(seq + base);
        *(int4*)&As[0][r2][c2 * 16 + 8] = *(const int4*)(seq + base + 8);
    }

    short8 bU[3][4];
    short8 bV[3][4];
#pragma unroll
    for (int g = 0; g < 3; ++g) {
        const int col = g * 64 + u;
#pragma unroll
        for (int ks = 0; ks < 4; ++ks) {
            short8 f, fv;
#pragma unroll
            for (int j = 0; j < 8; ++j) {
                int kp = ks * 32 + q * 8 + j;
                f[j]  = (short)U[(size_t)(kp >> 1) * 192 + col];
                fv[j] = (short)W[(size_t)kp * 192 + col];
            }
            bU[g][ks] = f;
            bV[g][ks] = fv;
        }
    }

    const float bz  = bf2f(bi[u])       + bf2f(br[u]);
    const float brg = bf2f(bi[64 + u])  + bf2f(br[64 + u]);
    const float bih = bf2f(bi[128 + u]);
    const float brh = bf2f(br[128 + u]);

    float hreg[2][4];
#pragma unroll
    for (int rt = 0; rt < 2; ++rt)
#pragma unroll
        for (int i = 0; i < 4; ++i) hreg[rt][i] = 0.0f;

    __syncthreads();

    const f32x4 Z4 = {0.f, 0.f, 0.f, 0.f};

    for (int t = 0; t < 72; ++t) {
        const int cur = t & 1, nb = cur ^ 1;

        int4 g0, g1;
        bool pf = (t < 71);
        if (pf) {
            const int tx = dir ? (70 - t) : (t + 1);
            size_t base = ((size_t)tx * bchunk + lb0 + r2) * 128 + c2 * 16;
            g0 = *(const int4*)(seq + base);
            g1 = *(const int4*)(seq + base + 8);
        }

        f32x4 acz[2], acr[2], ach[2], axz[2], axr[2], axh[2];
#pragma unroll
        for (int rt = 0; rt < 2; ++rt) {
            const unsigned short* ap = &Ah[cur][rt * 16 + ln][0];
            const unsigned short* sp = &As[cur][rt * 16 + ln][0];
            short8 a0 = *(const short8*)(ap + q * 8);
            short8 s0 = *(const short8*)(sp + q * 8);
            acz[rt] = MFMA_B16(a0, bU[0][0], Z4);
            acr[rt] = MFMA_B16(a0, bU[1][0], Z4);
            ach[rt] = MFMA_B16(a0, bU[2][0], Z4);
            axz[rt] = MFMA_B16(s0, bV[0][0], Z4);
            axr[rt] = MFMA_B16(s0, bV[1][0], Z4);
            axh[rt] = MFMA_B16(s0, bV[2][0], Z4);
#pragma unroll
            for (int ks = 1; ks < 4; ++ks) {
                short8 a = *(const short8*)(ap + ks * 32 + q * 8);
                short8 s = *(const short8*)(sp + ks * 32 + q * 8);
                acz[rt] = MFMA_B16(a, bU[0][ks], acz[rt]);
                acr[rt] = MFMA_B16(a, bU[1][ks], acr[rt]);
                ach[rt] = MFMA_B16(a, bU[2][ks], ach[rt]);
                axz[rt] = MFMA_B16(s, bV[0][ks], axz[rt]);
                axr[rt] = MFMA_B16(s, bV[1][ks], axr[rt]);
                axh[rt] = MFMA_B16(s, bV[2][ks], axh[rt]);
            }
        }

#pragma unroll
        for (int rt = 0; rt < 2; ++rt) {
#pragma unroll
            for (int i = 0; i < 4; ++i) {
                const int m = rt * 16 + q * 4 + i;
                float z = sigm(acz[rt][i] + axz[rt][i] + bz);
                float r = sigm(acr[rt][i] + axr[rt][i] + brg);
                float pre = axh[rt][i] + bih + r * (ach[rt][i] + brh);
                float hh = tanh_fast(pre);
                float hn = z * hreg[rt][i] + (1.0f - z) * hh;
                hreg[rt][i] = hn;
                unsigned short hi = f2bf(hn);
                unsigned short lo = f2bf(hn - bf2f(hi));
                *(unsigned int*)&Ah[nb][m][2 * u] = (unsigned int)hi | ((unsigned int)lo << 16);
            }
        }

        if (pf) {
            *(int4*)&As[nb][r2][c2 * 16]     = g0;
            *(int4*)&As[nb][r2][c2 * 16 + 8] = g1;
        }
        __syncthreads();
    }

#pragma unroll
    for (int rt = 0; rt < 2; ++rt) {
#pragma unroll
        for (int i = 0; i < 4; ++i) {
            const int m = rt * 16 + q * 4 + i;
            feat[(size_t)(gb0 + m) * 128 + dir * 64 + u] = hreg[rt][i];
        }
    }
}

// ---------------------------------------------------------------------------
// Head: relu(feat @ dense_W + dense_b) @ out_W + out_b -> softmax -> fp32 out
// ---------------------------------------------------------------------------
__global__ __launch_bounds__(256, 1)
void head_kernel(const float* __restrict__ feat,
                 const unsigned short* __restrict__ dW, const unsigned short* __restrict__ db,
                 const unsigned short* __restrict__ oW, const unsigned short* __restrict__ ob,
                 float* __restrict__ out)
{
    const int tid = threadIdx.x;
    const int b0  = blockIdx.x * 16;

    __shared__ __align__(16) unsigned short Wl[128][136];
    __shared__ __align__(16) float fs[16][128];
    __shared__ __align__(16) float hs[16][136];
    __shared__ __align__(16) float ls[16][32];

    for (int i = tid; i < 2048; i += 256) {
        const int k = i >> 4;
        const int c = (i & 15) * 8;
        *(int4*)&Wl[k][c] = *(const int4*)(dW + (size_t)k * 128 + c);
    }
    {
        const float4* src = (const float4*)(feat + (size_t)b0 * 128);
        float4* dst = (float4*)&fs[0][0];
        for (int i = tid; i < 512; i += 256) dst[i] = src[i];
    }
    __syncthreads();

    {
        const int row = tid >> 4;
        const int j0  = (tid & 15) * 8;
        float acc[8];
#pragma unroll
        for (int jj = 0; jj < 8; ++jj) acc[jj] = bf2f(db[j0 + jj]);
        for (int k = 0; k < 128; ++k) {
            float f = fs[row][k];
            short8 w = *(const short8*)&Wl[k][j0];
#pragma unroll
            for (int jj = 0; jj < 8; ++jj)
                acc[jj] += f * bf2f((unsigned short)w[jj]);
        }
#pragma unroll
        for (int jj = 0; jj < 8; ++jj) hs[row][j0 + jj] = fmaxf(acc[jj], 0.0f);
    }
    __syncthreads();

    for (int e = tid; e < 16 * 24; e += 256) {
        const int row = e / 24, l = e - 24 * row;
        float acc = bf2f(ob[l]);
        for (int k = 0; k < 128; ++k)
            acc += hs[row][k] * bf2f(oW[(size_t)k * 24 + l]);
        ls[row][l] = acc;
    }
    __syncthreads();

    for (int e = tid; e < 16 * 24; e += 256) {
        const int row = e / 24, l = e - 24 * row;
        float mx = ls[row][0];
#pragma unroll
        for (int k = 1; k < 24; ++k) mx = fmaxf(mx, ls[row][k]);
        float s = 0.0f;
#pragma unroll
        for (int k = 0; k < 24; ++k) s += __expf(ls[row][k] - mx);
        float v = __expf(ls[row][l] - mx) * __frcp_rn(s);
        out[(size_t)(b0 + row) * 24 + l] = v;
    }
}

// ---------------------------------------------------------------------------
extern "C" void kernel_launch(void* const* d_in, const int* in_sizes, int n_in,
                              void* d_out, int out_size, void* d_ws, size_t ws_size,
                              hipStream_t stream) {
    (void)in_sizes; (void)n_in; (void)out_size;

    // element counts of d_in[1..22] (everything except x)
    static const int wc[22] = {
        262144, 262144,          // h0_fwd, h0_bwd
        1728, 12288, 192, 192,   // d1f W,U,bi,br
        1728, 12288, 192, 192,   // d1b
        24576, 12288, 192, 192,  // d2f
        24576, 12288, 192, 192,  // d2b
        16384, 128,              // dense_W, dense_b
        3072, 24                 // out_W, out_b
    };

    WArgs a;
    int off = 0;
    for (int t = 0; t < 22; ++t) {
        a.src[t] = d_in[t + 1];
        a.off[t] = off;
        off += wc[t];
    }
    a.off[22] = off;                         // 647,192 elements

    // ws layout: [arena bf16 1.30 MB][feat fp32 2 MB][seq chunk bf16]
    const unsigned long long arena_bytes = 1294400ull;   // 647,192*2 rounded to 16
    const unsigned long long feat_bytes  = 4096ull * 128ull * 4ull;
    const unsigned long long seq_full    = 72ull * 4096ull * 128ull * 2ull;
    const unsigned long long fixed       = arena_bytes + feat_bytes;

    int nc = 32;
    for (int c = 1; c <= 32; c *= 2) {
        if (fixed + seq_full / (unsigned long long)c <= (unsigned long long)ws_size) { nc = c; break; }
    }
    const int bchunk = 4096 / nc;

    unsigned short* arena = (unsigned short*)d_ws;
    float* feat           = (float*)((char*)d_ws + arena_bytes);
    unsigned short* seq   = (unsigned short*)((char*)d_ws + fixed);

    convert_w<<<64, 256, 0, stream>>>(a, arena, (const unsigned short*)d_in[0]);

    const unsigned short* h0f  = arena + a.off[0];
    const unsigned short* h0b  = arena + a.off[1];
    const unsigned short* d1fW = arena + a.off[2];
    const unsigned short* d1fU = arena + a.off[3];
    const unsigned short* d1fbi= arena + a.off[4];
    const unsigned short* d1fbr= arena + a.off[5];
    const unsigned short* d1bW = arena + a.off[6];
    const unsigned short* d1bU = arena + a.off[7];
    const unsigned short* d1bbi= arena + a.off[8];
    const unsigned short* d1bbr= arena + a.off[9];
    const unsigned short* d2fW = arena + a.off[10];
    const unsigned short* d2fU = arena + a.off[11];
    const unsigned short* d2fbi= arena + a.off[12];
    const unsigned short* d2fbr= arena + a.off[13];
    const unsigned short* d2bW = arena + a.off[14];
    const unsigned short* d2bU = arena + a.off[15];
    const unsigned short* d2bbi= arena + a.off[16];
    const unsigned short* d2bbr= arena + a.off[17];
    const unsigned short* dW   = arena + a.off[18];
    const unsigned short* db   = arena + a.off[19];
    const unsigned short* oW   = arena + a.off[20];
    const unsigned short* ob   = arena + a.off[21];

    for (int c = 0; c < nc; ++c) {
        const int cb = c * bchunk;
        gru1_kernel<<<dim3(bchunk / 32, 2), 256, 0, stream>>>(
            d_in[0], cb, bchunk,
            h0f, h0b, d1fW, d1fU, d1fbi, d1fbr, d1bW, d1bU, d1bbi, d1bbr, seq);
        gru2_kernel<<<dim3(bchunk / 32, 2), 256, 0, stream>>>(
            seq, cb, bchunk,
            d2fW, d2fU, d2fbi, d2fbr, d2bW, d2bU, d2bbi, d2bbr, feat);
    }
    head_kernel<<<256, 256, 0, stream>>>(
        feat, dW, db, oW, ob, (float*)d_out);
}

// Round 6
// 342.685 us; speedup vs baseline: 1.2659x; 1.2659x over previous
//
#include <hip/hip_runtime.h>
#include <hip/hip_bf16.h>

typedef __attribute__((ext_vector_type(8))) short short8;
typedef __attribute__((ext_vector_type(4))) float f32x4;

#define MFMA_B16(a, b, c) __builtin_amdgcn_mfma_f32_16x16x32_bf16((a), (b), (c), 0, 0, 0)

__device__ __forceinline__ float bf2f(unsigned short u) {
    union { unsigned int i; float f; } v; v.i = ((unsigned int)u) << 16; return v.f;
}
__device__ __forceinline__ unsigned short f2bf(float f) {
    union { float f; unsigned int i; } v; v.f = f;
    unsigned int r = v.i + 0x7fffu + ((v.i >> 16) & 1u);
    return (unsigned short)(r >> 16);
}
__device__ __forceinline__ float sigm(float x) {
    return __frcp_rn(1.0f + __expf(-x));
}
__device__ __forceinline__ float tanh_fast(float x) {
    return 1.0f - 2.0f * __frcp_rn(__expf(2.0f * x) + 1.0f);
}

// probe 256 shorts: count bf16-plausible exponent fields. fp32-as-shorts ~138,
// bf16 ~256. threshold 200 discriminates. Deterministic per call.
__device__ __forceinline__ bool probe_bf16(const unsigned short* p, int tid, int* s_cnt) {
    if (tid == 0) *s_cnt = 0;
    __syncthreads();
    unsigned short s = p[tid & 255];
    int e = (s >> 7) & 0xFF;
    if (tid < 256 && e >= 117 && e <= 137) atomicAdd(s_cnt, 1);
    __syncthreads();
    return *s_cnt >= 200;
}

// ---------------------------------------------------------------------------
// Convert the 22 weight/bias/h0 tensors (everything except x) to a bf16 arena.
// ---------------------------------------------------------------------------
struct WArgs {
    const void* src[22];
    int off[23];   // arena element offsets (prefix); off[22] = total
};

__global__ __launch_bounds__(256)
void convert_w(WArgs a, unsigned short* __restrict__ arena,
               const unsigned short* __restrict__ probe)
{
    __shared__ int cnt;
    const bool bf = probe_bf16(probe, threadIdx.x, &cnt);
    const int total = a.off[22];
    for (int i = blockIdx.x * 256 + threadIdx.x; i < total; i += gridDim.x * 256) {
        int t = 0;
        while (t < 21 && i >= a.off[t + 1]) ++t;
        const int local = i - a.off[t];
        arena[i] = bf ? ((const unsigned short*)a.src[t])[local]
                      : f2bf(((const float*)a.src[t])[local]);
    }
}

// ---------------------------------------------------------------------------
// Layer 1: bidirectional GRU(64), relu candidate. 16-row tiles for occupancy
// (512 blocks = 2 blocks/CU). Reads x from d_in (dtype probed; fp32 split to
// hi/lo bf16 inline). Writes seq chunk (T, bchunk, 128) bf16.
// grid: (bchunk/16, 2), block 256 (4 waves; wave wv owns units wv*16..+15).
// ---------------------------------------------------------------------------
__global__ __launch_bounds__(256, 1)
void gru1_kernel(const void* __restrict__ X, int cb, int bchunk,
                 const unsigned short* __restrict__ h0f,
                 const unsigned short* __restrict__ h0b,
                 const unsigned short* __restrict__ Wf, const unsigned short* __restrict__ Uf,
                 const unsigned short* __restrict__ bif, const unsigned short* __restrict__ brf,
                 const unsigned short* __restrict__ Wb, const unsigned short* __restrict__ Ub,
                 const unsigned short* __restrict__ bib, const unsigned short* __restrict__ brb,
                 unsigned short* __restrict__ seq)
{
    const int tid  = threadIdx.x;
    const int lane = tid & 63;
    const int wv   = tid >> 6;
    const int q    = lane >> 4;
    const int ln   = lane & 15;
    const int dir  = blockIdx.y;
    const int lb0  = blockIdx.x * 16;        // local row base within chunk
    const int gb0  = cb + lb0;               // global batch row base
    const int u    = wv * 16 + ln;

    const unsigned short* W  = dir ? Wb  : Wf;
    const unsigned short* U  = dir ? Ub  : Uf;
    const unsigned short* bi = dir ? bib : bif;
    const unsigned short* br = dir ? brb : brf;
    const unsigned short* h0 = dir ? h0b : h0f;

    __shared__ __align__(16) unsigned short Ah[2][16][136];  // h hi/lo interleaved
    __shared__ __align__(16) unsigned short Ax[2][16][40];   // x hi/lo (18 real), rest 0
    __shared__ __align__(16) unsigned short stg[2][16][64];  // h-hi staging for seq
    __shared__ int s_cnt;

    const bool xbf = probe_bf16((const unsigned short*)X, tid, &s_cnt);

    // zero both Ax buffers (cols >=18 must stay 0 forever)
    {
        unsigned short* p = &Ax[0][0][0];
        for (int i = tid; i < 2 * 16 * 40; i += 256) p[i] = 0;
    }
    __syncthreads();

    // load x(t=0): 16 rows x 9 feats -> hi/lo pairs
    {
        const int tx0 = dir ? 71 : 0;
        if (tid < 144) {
            int r = tid / 9, k = tid - 9 * r;
            size_t idx = ((size_t)(gb0 + r) * 72 + tx0) * 9 + k;
            unsigned short hv, lv;
            if (xbf) { hv = ((const unsigned short*)X)[idx]; lv = 0; }
            else { float v = ((const float*)X)[idx]; hv = f2bf(v); lv = f2bf(v - bf2f(hv)); }
            Ax[0][r][2 * k]     = hv;
            Ax[0][r][2 * k + 1] = lv;
        }
    }

    // B-fragments: lane holds B[k=q*8+j][n=ln] of its wave's 16-col tile
    short8 bU[3][4];   // recurrent, K=128 hi/lo interleaved: U row = kp>>1
    short8 bW[3];      // x projection, K=32 (18 real hi/lo): W row = kp>>1
#pragma unroll
    for (int g = 0; g < 3; ++g) {
        const int col = g * 64 + u;
#pragma unroll
        for (int ks = 0; ks < 4; ++ks) {
            short8 f;
#pragma unroll
            for (int j = 0; j < 8; ++j) {
                int kp = ks * 32 + q * 8 + j;
                f[j] = (short)U[(size_t)(kp >> 1) * 192 + col];
            }
            bU[g][ks] = f;
        }
        short8 fw;
#pragma unroll
        for (int j = 0; j < 8; ++j) {
            int kp = q * 8 + j;
            fw[j] = (kp < 18) ? (short)W[(size_t)(kp >> 1) * 192 + col] : (short)0;
        }
        bW[g] = fw;
    }

    const float bz  = bf2f(bi[u])       + bf2f(br[u]);
    const float brg = bf2f(bi[64 + u])  + bf2f(br[64 + u]);
    const float bih = bf2f(bi[128 + u]);
    const float brh = bf2f(br[128 + u]);

    float hreg[4];
#pragma unroll
    for (int i = 0; i < 4; ++i) {
        int m = q * 4 + i;
        float hv = bf2f(h0[(size_t)(gb0 + m) * 64 + u]);
        hreg[i] = hv;
        unsigned short hi = f2bf(hv);
        unsigned short lo = f2bf(hv - bf2f(hi));
        *(unsigned int*)&Ah[0][m][2 * u] = (unsigned int)hi | ((unsigned int)lo << 16);
    }
    __syncthreads();

    const int r2 = tid >> 3, c2 = tid & 7;   // flush map: 16 rows x 8 int4 (tid<128)
    const int r0x = tid / 9, k0x = tid - 9 * r0x;  // x prefetch map (tid<144)
    const f32x4 Z4 = {0.f, 0.f, 0.f, 0.f};

    for (int t = 0; t < 72; ++t) {
        const int cur = t & 1, nb = cur ^ 1;

        // prefetch x(t+1): 144 feats -> hi/lo in registers
        unsigned short h0v = 0, l0v = 0;
        if (t < 71 && tid < 144) {
            const int tx = dir ? (70 - t) : (t + 1);
            size_t idx = ((size_t)(gb0 + r0x) * 72 + tx) * 9 + k0x;
            if (xbf) { h0v = ((const unsigned short*)X)[idx]; l0v = 0; }
            else { float v = ((const float*)X)[idx]; h0v = f2bf(v); l0v = f2bf(v - bf2f(h0v)); }
        }

        // flush previous step's h to seq (chunk-local indexing)
        if (t > 0 && tid < 128) {
            const int tw = dir ? (71 - (t - 1)) : (t - 1);
            int4 v = *(const int4*)&stg[nb][r2][c2 * 8];
            *(int4*)(seq + ((size_t)tw * bchunk + lb0 + r2) * 128 + dir * 64 + c2 * 8) = v;
        }

        // MFMA phase: 15 per wave
        f32x4 acz, acr, ach, axz, axr, axh;
        {
            const unsigned short* ap = &Ah[cur][ln][0];
            short8 a0 = *(const short8*)(ap + q * 8);
            acz = MFMA_B16(a0, bU[0][0], Z4);
            acr = MFMA_B16(a0, bU[1][0], Z4);
            ach = MFMA_B16(a0, bU[2][0], Z4);
#pragma unroll
            for (int ks = 1; ks < 4; ++ks) {
                short8 a = *(const short8*)(ap + ks * 32 + q * 8);
                acz = MFMA_B16(a, bU[0][ks], acz);
                acr = MFMA_B16(a, bU[1][ks], acr);
                ach = MFMA_B16(a, bU[2][ks], ach);
            }
            short8 ax = *(const short8*)(&Ax[cur][ln][q * 8]);
            axz = MFMA_B16(ax, bW[0], Z4);
            axr = MFMA_B16(ax, bW[1], Z4);
            axh = MFMA_B16(ax, bW[2], Z4);
        }

        // gates + state update (4 rows per lane)
#pragma unroll
        for (int i = 0; i < 4; ++i) {
            const int m = q * 4 + i;
            float z = sigm(acz[i] + axz[i] + bz);
            float r = sigm(acr[i] + axr[i] + brg);
            float pre = axh[i] + bih + r * (ach[i] + brh);
            float hh = fmaxf(pre, 0.0f);
            float hn = z * hreg[i] + (1.0f - z) * hh;
            hreg[i] = hn;
            unsigned short hi = f2bf(hn);
            unsigned short lo = f2bf(hn - bf2f(hi));
            *(unsigned int*)&Ah[nb][m][2 * u] = (unsigned int)hi | ((unsigned int)lo << 16);
            stg[cur][m][u] = hi;
        }

        if (t < 71 && tid < 144) {
            Ax[nb][r0x][2 * k0x]     = h0v;
            Ax[nb][r0x][2 * k0x + 1] = l0v;
        }
        __syncthreads();
    }

    if (tid < 128) {
        const int tw = dir ? 0 : 71;
        int4 v = *(const int4*)&stg[1][r2][c2 * 8];
        *(int4*)(seq + ((size_t)tw * bchunk + lb0 + r2) * 128 + dir * 64 + c2 * 8) = v;
    }
}

// ---------------------------------------------------------------------------
// Layer 2: bidirectional GRU(64), tanh, input = seq chunk (T,bchunk,128),
// zero init, fused input projection, final states -> feat (B,128) fp32.
// 16-row tiles; grid (bchunk/16, 2), block 256.
// ---------------------------------------------------------------------------
__global__ __launch_bounds__(256, 1)
void gru2_kernel(const unsigned short* __restrict__ seq, int cb, int bchunk,
                 const unsigned short* __restrict__ W2f, const unsigned short* __restrict__ U2f,
                 const unsigned short* __restrict__ bi2f, const unsigned short* __restrict__ br2f,
                 const unsigned short* __restrict__ W2b, const unsigned short* __restrict__ U2b,
                 const unsigned short* __restrict__ bi2b, const unsigned short* __restrict__ br2b,
                 float* __restrict__ feat)
{
    const int tid  = threadIdx.x;
    const int lane = tid & 63;
    const int wv   = tid >> 6;
    const int q    = lane >> 4;
    const int ln   = lane & 15;
    const int dir  = blockIdx.y;
    const int lb0  = blockIdx.x * 16;
    const int gb0  = cb + lb0;
    const int u    = wv * 16 + ln;

    const unsigned short* W  = dir ? W2b  : W2f;
    const unsigned short* U  = dir ? U2b  : U2f;
    const unsigned short* bi = dir ? bi2b : bi2f;
    const unsigned short* br = dir ? br2b : br2f;

    __shared__ __align__(16) unsigned short Ah[2][16][136];
    __shared__ __align__(16) unsigned short As[2][16][136];

    {
        unsigned short* p = &Ah[0][0][0];
        for (int i = tid; i < 16 * 136; i += 256) p[i] = 0;
    }

    const int r3 = tid >> 4, c3 = tid & 15;   // seq prefetch: 16 rows x 16 int4
    {
        const int tx0 = dir ? 71 : 0;
        size_t base = ((size_t)tx0 * bchunk + lb0 + r3) * 128 + c3 * 8;
        *(int4*)&As[0][r3][c3 * 8] = *(const int4*)(seq + base);
    }

    short8 bU[3][4];
    short8 bV[3][4];
#pragma unroll
    for (int g = 0; g < 3; ++g) {
        const int col = g * 64 + u;
#pragma unroll
        for (int ks = 0; ks < 4; ++ks) {
            short8 f, fv;
#pragma unroll
            for (int j = 0; j < 8; ++j) {
                int kp = ks * 32 + q * 8 + j;
                f[j]  = (short)U[(size_t)(kp >> 1) * 192 + col];
                fv[j] = (short)W[(size_t)kp * 192 + col];
            }
            bU[g][ks] = f;
            bV[g][ks] = fv;
        }
    }

    const float bz  = bf2f(bi[u])       + bf2f(br[u]);
    const float brg = bf2f(bi[64 + u])  + bf2f(br[64 + u]);
    const float bih = bf2f(bi[128 + u]);
    const float brh = bf2f(br[128 + u]);

    float hreg[4];
#pragma unroll
    for (int i = 0; i < 4; ++i) hreg[i] = 0.0f;

    __syncthreads();

    const f32x4 Z4 = {0.f, 0.f, 0.f, 0.f};

    for (int t = 0; t < 72; ++t) {
        const int cur = t & 1, nb = cur ^ 1;

        int4 g0;
        bool pf = (t < 71);
        if (pf) {
            const int tx = dir ? (70 - t) : (t + 1);
            size_t base = ((size_t)tx * bchunk + lb0 + r3) * 128 + c3 * 8;
            g0 = *(const int4*)(seq + base);
        }

        f32x4 acz, acr, ach, axz, axr, axh;
        {
            const unsigned short* ap = &Ah[cur][ln][0];
            const unsigned short* sp = &As[cur][ln][0];
            short8 a0 = *(const short8*)(ap + q * 8);
            short8 s0 = *(const short8*)(sp + q * 8);
            acz = MFMA_B16(a0, bU[0][0], Z4);
            acr = MFMA_B16(a0, bU[1][0], Z4);
            ach = MFMA_B16(a0, bU[2][0], Z4);
            axz = MFMA_B16(s0, bV[0][0], Z4);
            axr = MFMA_B16(s0, bV[1][0], Z4);
            axh = MFMA_B16(s0, bV[2][0], Z4);
#pragma unroll
            for (int ks = 1; ks < 4; ++ks) {
                short8 a = *(const short8*)(ap + ks * 32 + q * 8);
                short8 s = *(const short8*)(sp + ks * 32 + q * 8);
                acz = MFMA_B16(a, bU[0][ks], acz);
                acr = MFMA_B16(a, bU[1][ks], acr);
                ach = MFMA_B16(a, bU[2][ks], ach);
                axz = MFMA_B16(s, bV[0][ks], axz);
                axr = MFMA_B16(s, bV[1][ks], axr);
                axh = MFMA_B16(s, bV[2][ks], axh);
            }
        }

#pragma unroll
        for (int i = 0; i < 4; ++i) {
            const int m = q * 4 + i;
            float z = sigm(acz[i] + axz[i] + bz);
            float r = sigm(acr[i] + axr[i] + brg);
            float pre = axh[i] + bih + r * (ach[i] + brh);
            float hh = tanh_fast(pre);
            float hn = z * hreg[i] + (1.0f - z) * hh;
            hreg[i] = hn;
            unsigned short hi = f2bf(hn);
            unsigned short lo = f2bf(hn - bf2f(hi));
            *(unsigned int*)&Ah[nb][m][2 * u] = (unsigned int)hi | ((unsigned int)lo << 16);
        }

        if (pf) {
            *(int4*)&As[nb][r3][c3 * 8] = g0;
        }
        __syncthreads();
    }

#pragma unroll
    for (int i = 0; i < 4; ++i) {
        const int m = q * 4 + i;
        feat[(size_t)(gb0 + m) * 128 + dir * 64 + u] = hreg[i];
    }
}

// ---------------------------------------------------------------------------
// Head: relu(feat @ dense_W + dense_b) @ out_W + out_b -> softmax -> fp32 out
// ---------------------------------------------------------------------------
__global__ __launch_bounds__(256, 1)
void head_kernel(const float* __restrict__ feat,
                 const unsigned short* __restrict__ dW, const unsigned short* __restrict__ db,
                 const unsigned short* __restrict__ oW, const unsigned short* __restrict__ ob,
                 float* __restrict__ out)
{
    const int tid = threadIdx.x;
    const int b0  = blockIdx.x * 16;

    __shared__ __align__(16) unsigned short Wl[128][136];
    __shared__ __align__(16) float fs[16][128];
    __shared__ __align__(16) float hs[16][136];
    __shared__ __align__(16) float ls[16][32];

    for (int i = tid; i < 2048; i += 256) {
        const int k = i >> 4;
        const int c = (i & 15) * 8;
        *(int4*)&Wl[k][c] = *(const int4*)(dW + (size_t)k * 128 + c);
    }
    {
        const float4* src = (const float4*)(feat + (size_t)b0 * 128);
        float4* dst = (float4*)&fs[0][0];
        for (int i = tid; i < 512; i += 256) dst[i] = src[i];
    }
    __syncthreads();

    {
        const int row = tid >> 4;
        const int j0  = (tid & 15) * 8;
        float acc[8];
#pragma unroll
        for (int jj = 0; jj < 8; ++jj) acc[jj] = bf2f(db[j0 + jj]);
        for (int k = 0; k < 128; ++k) {
            float f = fs[row][k];
            short8 w = *(const short8*)&Wl[k][j0];
#pragma unroll
            for (int jj = 0; jj < 8; ++jj)
                acc[jj] += f * bf2f((unsigned short)w[jj]);
        }
#pragma unroll
        for (int jj = 0; jj < 8; ++jj) hs[row][j0 + jj] = fmaxf(acc[jj], 0.0f);
    }
    __syncthreads();

    for (int e = tid; e < 16 * 24; e += 256) {
        const int row = e / 24, l = e - 24 * row;
        float acc = bf2f(ob[l]);
        for (int k = 0; k < 128; ++k)
            acc += hs[row][k] * bf2f(oW[(size_t)k * 24 + l]);
        ls[row][l] = acc;
    }
    __syncthreads();

    for (int e = tid; e < 16 * 24; e += 256) {
        const int row = e / 24, l = e - 24 * row;
        float mx = ls[row][0];
#pragma unroll
        for (int k = 1; k < 24; ++k) mx = fmaxf(mx, ls[row][k]);
        float s = 0.0f;
#pragma unroll
        for (int k = 0; k < 24; ++k) s += __expf(ls[row][k] - mx);
        float v = __expf(ls[row][l] - mx) * __frcp_rn(s);
        out[(size_t)(b0 + row) * 24 + l] = v;
    }
}

// ---------------------------------------------------------------------------
extern "C" void kernel_launch(void* const* d_in, const int* in_sizes, int n_in,
                              void* d_out, int out_size, void* d_ws, size_t ws_size,
                              hipStream_t stream) {
    (void)in_sizes; (void)n_in; (void)out_size;

    // element counts of d_in[1..22] (everything except x)
    static const int wc[22] = {
        262144, 262144,          // h0_fwd, h0_bwd
        1728, 12288, 192, 192,   // d1f W,U,bi,br
        1728, 12288, 192, 192,   // d1b
        24576, 12288, 192, 192,  // d2f
        24576, 12288, 192, 192,  // d2b
        16384, 128,              // dense_W, dense_b
        3072, 24                 // out_W, out_b
    };

    WArgs a;
    int off = 0;
    for (int t = 0; t < 22; ++t) {
        a.src[t] = d_in[t + 1];
        a.off[t] = off;
        off += wc[t];
    }
    a.off[22] = off;                         // 647,192 elements

    // ws layout: [arena bf16 1.30 MB][feat fp32 2 MB][seq chunk bf16]
    const unsigned long long arena_bytes = 1294400ull;
    const unsigned long long feat_bytes  = 4096ull * 128ull * 4ull;
    const unsigned long long seq_full    = 72ull * 4096ull * 128ull * 2ull;
    const unsigned long long fixed       = arena_bytes + feat_bytes;

    int nc = 32;
    for (int c = 1; c <= 32; c *= 2) {
        if (fixed + seq_full / (unsigned long long)c <= (unsigned long long)ws_size) { nc = c; break; }
    }
    const int bchunk = 4096 / nc;

    unsigned short* arena = (unsigned short*)d_ws;
    float* feat           = (float*)((char*)d_ws + arena_bytes);
    unsigned short* seq   = (unsigned short*)((char*)d_ws + fixed);

    convert_w<<<64, 256, 0, stream>>>(a, arena, (const unsigned short*)d_in[0]);

    const unsigned short* h0f  = arena + a.off[0];
    const unsigned short* h0b  = arena + a.off[1];
    const unsigned short* d1fW = arena + a.off[2];
    const unsigned short* d1fU = arena + a.off[3];
    const unsigned short* d1fbi= arena + a.off[4];
    const unsigned short* d1fbr= arena + a.off[5];
    const unsigned short* d1bW = arena + a.off[6];
    const unsigned short* d1bU = arena + a.off[7];
    const unsigned short* d1bbi= arena + a.off[8];
    const unsigned short* d1bbr= arena + a.off[9];
    const unsigned short* d2fW = arena + a.off[10];
    const unsigned short* d2fU = arena + a.off[11];
    const unsigned short* d2fbi= arena + a.off[12];
    const unsigned short* d2fbr= arena + a.off[13];
    const unsigned short* d2bW = arena + a.off[14];
    const unsigned short* d2bU = arena + a.off[15];
    const unsigned short* d2bbi= arena + a.off[16];
    const unsigned short* d2bbr= arena + a.off[17];
    const unsigned short* dW   = arena + a.off[18];
    const unsigned short* db   = arena + a.off[19];
    const unsigned short* oW   = arena + a.off[20];
    const unsigned short* ob   = arena + a.off[21];

    for (int c = 0; c < nc; ++c) {
        const int cb = c * bchunk;
        gru1_kernel<<<dim3(bchunk / 16, 2), 256, 0, stream>>>(
            d_in[0], cb, bchunk,
            h0f, h0b, d1fW, d1fU, d1fbi, d1fbr, d1bW, d1bU, d1bbi, d1bbr, seq);
        gru2_kernel<<<dim3(bchunk / 16, 2), 256, 0, stream>>>(
            seq, cb, bchunk,
            d2fW, d2fU, d2fbi, d2fbr, d2bW, d2bU, d2bbi, d2bbr, feat);
    }
    head_kernel<<<256, 256, 0, stream>>>(
        feat, dW, db, oW, ob, (float*)d_out);
}

// Round 7
// 319.046 us; speedup vs baseline: 1.3597x; 1.0741x over previous
//
#include <hip/hip_runtime.h>
#include <hip/hip_bf16.h>

typedef __attribute__((ext_vector_type(8))) short short8;
typedef __attribute__((ext_vector_type(4))) float f32x4;

#define MFMA_B16(a, b, c) __builtin_amdgcn_mfma_f32_16x16x32_bf16((a), (b), (c), 0, 0, 0)

__device__ __forceinline__ float bf2f(unsigned short u) {
    union { unsigned int i; float f; } v; v.i = ((unsigned int)u) << 16; return v.f;
}
__device__ __forceinline__ unsigned short f2bf(float f) {
    union { float f; unsigned int i; } v; v.f = f;
    unsigned int r = v.i + 0x7fffu + ((v.i >> 16) & 1u);
    return (unsigned short)(r >> 16);
}
__device__ __forceinline__ float sigm(float x) {
    return __frcp_rn(1.0f + __expf(-x));
}
__device__ __forceinline__ float tanh_fast(float x) {
    return 1.0f - 2.0f * __frcp_rn(__expf(2.0f * x) + 1.0f);
}

// probe 256 shorts: count bf16-plausible exponent fields. fp32-as-shorts ~138,
// bf16 ~256. threshold 200 discriminates. Deterministic per call.
__device__ __forceinline__ bool probe_bf16(const unsigned short* p, int tid, int* s_cnt) {
    if (tid == 0) *s_cnt = 0;
    __syncthreads();
    unsigned short s = p[tid & 255];
    int e = (s >> 7) & 0xFF;
    if (tid < 256 && e >= 117 && e <= 137) atomicAdd(s_cnt, 1);
    __syncthreads();
    return *s_cnt >= 200;
}

// ---------------------------------------------------------------------------
// Convert the 22 weight/bias/h0 tensors (everything except x) to a bf16 arena.
// ---------------------------------------------------------------------------
struct WArgs {
    const void* src[22];
    int off[23];
};

__global__ __launch_bounds__(256)
void convert_w(WArgs a, unsigned short* __restrict__ arena,
               const unsigned short* __restrict__ probe)
{
    __shared__ int cnt;
    const bool bf = probe_bf16(probe, threadIdx.x, &cnt);
    const int total = a.off[22];
    for (int i = blockIdx.x * 256 + threadIdx.x; i < total; i += gridDim.x * 256) {
        int t = 0;
        while (t < 21 && i >= a.off[t + 1]) ++t;
        const int local = i - a.off[t];
        arena[i] = bf ? ((const unsigned short*)a.src[t])[local]
                      : f2bf(((const float*)a.src[t])[local]);
    }
}

// ---------------------------------------------------------------------------
// Layer 1: bidirectional GRU(64), relu candidate. h state bf16 (K=64 recurrent),
// x hi/lo bf16 (K=32). Biases folded into MFMA C-init; z/r input+recurrent
// chained. Writes seq chunk (T,bchunk,128) bf16 directly from Ah.
// grid: (bchunk/16, 2), block 256.
// ---------------------------------------------------------------------------
__global__ __launch_bounds__(256, 1)
void gru1_kernel(const void* __restrict__ X, int cb, int bchunk,
                 const unsigned short* __restrict__ h0f,
                 const unsigned short* __restrict__ h0b,
                 const unsigned short* __restrict__ Wf, const unsigned short* __restrict__ Uf,
                 const unsigned short* __restrict__ bif, const unsigned short* __restrict__ brf,
                 const unsigned short* __restrict__ Wb, const unsigned short* __restrict__ Ub,
                 const unsigned short* __restrict__ bib, const unsigned short* __restrict__ brb,
                 unsigned short* __restrict__ seq)
{
    const int tid  = threadIdx.x;
    const int lane = tid & 63;
    const int wv   = tid >> 6;
    const int q    = lane >> 4;
    const int ln   = lane & 15;
    const int dir  = blockIdx.y;
    const int lb0  = blockIdx.x * 16;
    const int gb0  = cb + lb0;
    const int u    = wv * 16 + ln;

    const unsigned short* W  = dir ? Wb  : Wf;
    const unsigned short* U  = dir ? Ub  : Uf;
    const unsigned short* bi = dir ? bib : bif;
    const unsigned short* br = dir ? brb : brf;
    const unsigned short* h0 = dir ? h0b : h0f;

    __shared__ __align__(16) unsigned short Ah[2][16][80];   // h bf16, 64 units (+16 pad)
    __shared__ __align__(16) unsigned short Ax[2][16][40];   // x hi/lo (18 real), rest 0
    __shared__ int s_cnt;

    const bool xbf = probe_bf16((const unsigned short*)X, tid, &s_cnt);

    // zero both Ax buffers (cols >=18 must stay 0 forever)
    {
        unsigned short* p = &Ax[0][0][0];
        for (int i = tid; i < 2 * 16 * 40; i += 256) p[i] = 0;
    }
    __syncthreads();

    // load x(t=0): 16 rows x 9 feats -> hi/lo pairs
    {
        const int tx0 = dir ? 71 : 0;
        if (tid < 144) {
            int r = tid / 9, k = tid - 9 * r;
            size_t idx = ((size_t)(gb0 + r) * 72 + tx0) * 9 + k;
            unsigned short hv, lv;
            if (xbf) { hv = ((const unsigned short*)X)[idx]; lv = 0; }
            else { float v = ((const float*)X)[idx]; hv = f2bf(v); lv = f2bf(v - bf2f(hv)); }
            Ax[0][r][2 * k]     = hv;
            Ax[0][r][2 * k + 1] = lv;
        }
    }

    // B-fragments: lane holds B[k=q*8+j][n=ln] of its wave's 16-col tile
    short8 bU[3][2];   // recurrent, K=64 direct
    short8 bW[3];      // x projection, K=32 (18 real hi/lo): W row = kp>>1
#pragma unroll
    for (int g = 0; g < 3; ++g) {
        const int col = g * 64 + u;
#pragma unroll
        for (int ks = 0; ks < 2; ++ks) {
            short8 f;
#pragma unroll
            for (int j = 0; j < 8; ++j) {
                int kp = ks * 32 + q * 8 + j;
                f[j] = (short)U[(size_t)kp * 192 + col];
            }
            bU[g][ks] = f;
        }
        short8 fw;
#pragma unroll
        for (int j = 0; j < 8; ++j) {
            int kp = q * 8 + j;
            fw[j] = (kp < 18) ? (short)W[(size_t)(kp >> 1) * 192 + col] : (short)0;
        }
        bW[g] = fw;
    }

    const float bz  = bf2f(bi[u])       + bf2f(br[u]);
    const float brg = bf2f(bi[64 + u])  + bf2f(br[64 + u]);
    const float bih = bf2f(bi[128 + u]);
    const float brh = bf2f(br[128 + u]);
    const f32x4 Cz  = {bz,  bz,  bz,  bz};
    const f32x4 Cr  = {brg, brg, brg, brg};
    const f32x4 Chx = {bih, bih, bih, bih};
    const f32x4 Chr = {brh, brh, brh, brh};

    float hreg[4];
#pragma unroll
    for (int i = 0; i < 4; ++i) {
        int m = q * 4 + i;
        float hv = bf2f(h0[(size_t)(gb0 + m) * 64 + u]);
        hreg[i] = hv;
        Ah[0][m][u] = f2bf(hv);
    }
    __syncthreads();

    const int r2 = tid >> 3, c2 = tid & 7;           // flush map (tid<128)
    const int r0x = tid / 9, k0x = tid - 9 * r0x;    // x prefetch map (tid<144)

    for (int t = 0; t < 72; ++t) {
        const int cur = t & 1, nb = cur ^ 1;

        // prefetch x(t+1) into registers
        unsigned short h0v = 0, l0v = 0;
        if (t < 71 && tid < 144) {
            const int tx = dir ? (70 - t) : (t + 1);
            size_t idx = ((size_t)(gb0 + r0x) * 72 + tx) * 9 + k0x;
            if (xbf) { h0v = ((const unsigned short*)X)[idx]; l0v = 0; }
            else { float v = ((const float*)X)[idx]; h0v = f2bf(v); l0v = f2bf(v - bf2f(h0v)); }
        }

        // flush h(t-1) (= Ah[cur]) to seq, coalesced
        if (t > 0 && tid < 128) {
            const int tw = dir ? (71 - (t - 1)) : (t - 1);
            int4 v = *(const int4*)&Ah[cur][r2][c2 * 8];
            *(int4*)(seq + ((size_t)tw * bchunk + lb0 + r2) * 128 + dir * 64 + c2 * 8) = v;
        }

        // MFMA phase: 9 per wave (bias-init, z/r chained)
        const unsigned short* ap = &Ah[cur][ln][0];
        short8 a0 = *(const short8*)(ap + q * 8);
        short8 a1 = *(const short8*)(ap + 32 + q * 8);
        short8 ax = *(const short8*)(&Ax[cur][ln][q * 8]);
        f32x4 az  = MFMA_B16(ax, bW[0], Cz);
        az        = MFMA_B16(a0, bU[0][0], az);
        az        = MFMA_B16(a1, bU[0][1], az);
        f32x4 ar  = MFMA_B16(ax, bW[1], Cr);
        ar        = MFMA_B16(a0, bU[1][0], ar);
        ar        = MFMA_B16(a1, bU[1][1], ar);
        f32x4 ahx = MFMA_B16(ax, bW[2], Chx);
        f32x4 ahr = MFMA_B16(a0, bU[2][0], Chr);
        ahr       = MFMA_B16(a1, bU[2][1], ahr);

        // gates + state update
#pragma unroll
        for (int i = 0; i < 4; ++i) {
            const int m = q * 4 + i;
            float z = sigm(az[i]);
            float r = sigm(ar[i]);
            float pre = ahx[i] + r * ahr[i];
            float hh = fmaxf(pre, 0.0f);
            float hn = hh + z * (hreg[i] - hh);
            hreg[i] = hn;
            Ah[nb][m][u] = f2bf(hn);
        }

        if (t < 71 && tid < 144) {
            Ax[nb][r0x][2 * k0x]     = h0v;
            Ax[nb][r0x][2 * k0x + 1] = l0v;
        }
        __syncthreads();
    }

    // final flush: h(71) lives in Ah[0]
    if (tid < 128) {
        const int tw = dir ? 0 : 71;
        int4 v = *(const int4*)&Ah[0][r2][c2 * 8];
        *(int4*)(seq + ((size_t)tw * bchunk + lb0 + r2) * 128 + dir * 64 + c2 * 8) = v;
    }
}

// ---------------------------------------------------------------------------
// Layer 2: bidirectional GRU(64), tanh, input = seq chunk (T,bchunk,128),
// zero init, h bf16 (K=64 recurrent), fused chains + bias C-init.
// Final states -> feat (B,128) fp32. grid (bchunk/16, 2), block 256.
// ---------------------------------------------------------------------------
__global__ __launch_bounds__(256, 1)
void gru2_kernel(const unsigned short* __restrict__ seq, int cb, int bchunk,
                 const unsigned short* __restrict__ W2f, const unsigned short* __restrict__ U2f,
                 const unsigned short* __restrict__ bi2f, const unsigned short* __restrict__ br2f,
                 const unsigned short* __restrict__ W2b, const unsigned short* __restrict__ U2b,
                 const unsigned short* __restrict__ bi2b, const unsigned short* __restrict__ br2b,
                 float* __restrict__ feat)
{
    const int tid  = threadIdx.x;
    const int lane = tid & 63;
    const int wv   = tid >> 6;
    const int q    = lane >> 4;
    const int ln   = lane & 15;
    const int dir  = blockIdx.y;
    const int lb0  = blockIdx.x * 16;
    const int gb0  = cb + lb0;
    const int u    = wv * 16 + ln;

    const unsigned short* W  = dir ? W2b  : W2f;
    const unsigned short* U  = dir ? U2b  : U2f;
    const unsigned short* bi = dir ? bi2b : bi2f;
    const unsigned short* br = dir ? br2b : br2f;

    __shared__ __align__(16) unsigned short Ah[2][16][80];   // h bf16
    __shared__ __align__(16) unsigned short As[2][16][144];  // seq slice K=128 (+16 pad)

    {
        unsigned short* p = &Ah[0][0][0];
        for (int i = tid; i < 2 * 16 * 80; i += 256) p[i] = 0;
    }

    const int r3 = tid >> 4, c3 = tid & 15;   // seq prefetch: 16 rows x 16 int4
    {
        const int tx0 = dir ? 71 : 0;
        size_t base = ((size_t)tx0 * bchunk + lb0 + r3) * 128 + c3 * 8;
        *(int4*)&As[0][r3][c3 * 8] = *(const int4*)(seq + base);
    }

    short8 bU[3][2];   // recurrent K=64
    short8 bV[3][4];   // input projection K=128
#pragma unroll
    for (int g = 0; g < 3; ++g) {
        const int col = g * 64 + u;
#pragma unroll
        for (int ks = 0; ks < 2; ++ks) {
            short8 f;
#pragma unroll
            for (int j = 0; j < 8; ++j) {
                int kp = ks * 32 + q * 8 + j;
                f[j] = (short)U[(size_t)kp * 192 + col];
            }
            bU[g][ks] = f;
        }
#pragma unroll
        for (int ks = 0; ks < 4; ++ks) {
            short8 fv;
#pragma unroll
            for (int j = 0; j < 8; ++j) {
                int kp = ks * 32 + q * 8 + j;
                fv[j] = (short)W[(size_t)kp * 192 + col];
            }
            bV[g][ks] = fv;
        }
    }

    const float bz  = bf2f(bi[u])       + bf2f(br[u]);
    const float brg = bf2f(bi[64 + u])  + bf2f(br[64 + u]);
    const float bih = bf2f(bi[128 + u]);
    const float brh = bf2f(br[128 + u]);
    const f32x4 Cz  = {bz,  bz,  bz,  bz};
    const f32x4 Cr  = {brg, brg, brg, brg};
    const f32x4 Chx = {bih, bih, bih, bih};
    const f32x4 Chr = {brh, brh, brh, brh};

    float hreg[4];
#pragma unroll
    for (int i = 0; i < 4; ++i) hreg[i] = 0.0f;

    __syncthreads();

    for (int t = 0; t < 72; ++t) {
        const int cur = t & 1, nb = cur ^ 1;

        int4 g0;
        bool pf = (t < 71);
        if (pf) {
            const int tx = dir ? (70 - t) : (t + 1);
            size_t base = ((size_t)tx * bchunk + lb0 + r3) * 128 + c3 * 8;
            g0 = *(const int4*)(seq + base);
        }

        const unsigned short* ap = &Ah[cur][ln][0];
        const unsigned short* sp = &As[cur][ln][0];
        short8 a0 = *(const short8*)(ap + q * 8);
        short8 a1 = *(const short8*)(ap + 32 + q * 8);
        short8 s0 = *(const short8*)(sp + q * 8);
        short8 s1 = *(const short8*)(sp + 32 + q * 8);
        short8 s2 = *(const short8*)(sp + 64 + q * 8);
        short8 s3 = *(const short8*)(sp + 96 + q * 8);

        f32x4 az  = MFMA_B16(s0, bV[0][0], Cz);
        az        = MFMA_B16(s1, bV[0][1], az);
        az        = MFMA_B16(s2, bV[0][2], az);
        az        = MFMA_B16(s3, bV[0][3], az);
        az        = MFMA_B16(a0, bU[0][0], az);
        az        = MFMA_B16(a1, bU[0][1], az);
        f32x4 ar  = MFMA_B16(s0, bV[1][0], Cr);
        ar        = MFMA_B16(s1, bV[1][1], ar);
        ar        = MFMA_B16(s2, bV[1][2], ar);
        ar        = MFMA_B16(s3, bV[1][3], ar);
        ar        = MFMA_B16(a0, bU[1][0], ar);
        ar        = MFMA_B16(a1, bU[1][1], ar);
        f32x4 ahx = MFMA_B16(s0, bV[2][0], Chx);
        ahx       = MFMA_B16(s1, bV[2][1], ahx);
        ahx       = MFMA_B16(s2, bV[2][2], ahx);
        ahx       = MFMA_B16(s3, bV[2][3], ahx);
        f32x4 ahr = MFMA_B16(a0, bU[2][0], Chr);
        ahr       = MFMA_B16(a1, bU[2][1], ahr);

#pragma unroll
        for (int i = 0; i < 4; ++i) {
            const int m = q * 4 + i;
            float z = sigm(az[i]);
            float r = sigm(ar[i]);
            float pre = ahx[i] + r * ahr[i];
            float hh = tanh_fast(pre);
            float hn = hh + z * (hreg[i] - hh);
            hreg[i] = hn;
            Ah[nb][m][u] = f2bf(hn);
        }

        if (pf) {
            *(int4*)&As[nb][r3][c3 * 8] = g0;
        }
        __syncthreads();
    }

#pragma unroll
    for (int i = 0; i < 4; ++i) {
        const int m = q * 4 + i;
        feat[(size_t)(gb0 + m) * 128 + dir * 64 + u] = hreg[i];
    }
}

// ---------------------------------------------------------------------------
// Head: relu(feat @ dense_W + dense_b) @ out_W + out_b -> softmax -> fp32 out
// ---------------------------------------------------------------------------
__global__ __launch_bounds__(256, 1)
void head_kernel(const float* __restrict__ feat,
                 const unsigned short* __restrict__ dW, const unsigned short* __restrict__ db,
                 const unsigned short* __restrict__ oW, const unsigned short* __restrict__ ob,
                 float* __restrict__ out)
{
    const int tid = threadIdx.x;
    const int b0  = blockIdx.x * 16;

    __shared__ __align__(16) unsigned short Wl[128][136];
    __shared__ __align__(16) float fs[16][128];
    __shared__ __align__(16) float hs[16][136];
    __shared__ __align__(16) float ls[16][32];

    for (int i = tid; i < 2048; i += 256) {
        const int k = i >> 4;
        const int c = (i & 15) * 8;
        *(int4*)&Wl[k][c] = *(const int4*)(dW + (size_t)k * 128 + c);
    }
    {
        const float4* src = (const float4*)(feat + (size_t)b0 * 128);
        float4* dst = (float4*)&fs[0][0];
        for (int i = tid; i < 512; i += 256) dst[i] = src[i];
    }
    __syncthreads();

    {
        const int row = tid >> 4;
        const int j0  = (tid & 15) * 8;
        float acc[8];
#pragma unroll
        for (int jj = 0; jj < 8; ++jj) acc[jj] = bf2f(db[j0 + jj]);
        for (int k = 0; k < 128; ++k) {
            float f = fs[row][k];
            short8 w = *(const short8*)&Wl[k][j0];
#pragma unroll
            for (int jj = 0; jj < 8; ++jj)
                acc[jj] += f * bf2f((unsigned short)w[jj]);
        }
#pragma unroll
        for (int jj = 0; jj < 8; ++jj) hs[row][j0 + jj] = fmaxf(acc[jj], 0.0f);
    }
    __syncthreads();

    for (int e = tid; e < 16 * 24; e += 256) {
        const int row = e / 24, l = e - 24 * row;
        float acc = bf2f(ob[l]);
        for (int k = 0; k < 128; ++k)
            acc += hs[row][k] * bf2f(oW[(size_t)k * 24 + l]);
        ls[row][l] = acc;
    }
    __syncthreads();

    for (int e = tid; e < 16 * 24; e += 256) {
        const int row = e / 24, l = e - 24 * row;
        float mx = ls[row][0];
#pragma unroll
        for (int k = 1; k < 24; ++k) mx = fmaxf(mx, ls[row][k]);
        float s = 0.0f;
#pragma unroll
        for (int k = 0; k < 24; ++k) s += __expf(ls[row][k] - mx);
        float v = __expf(ls[row][l] - mx) * __frcp_rn(s);
        out[(size_t)(b0 + row) * 24 + l] = v;
    }
}

// ---------------------------------------------------------------------------
extern "C" void kernel_launch(void* const* d_in, const int* in_sizes, int n_in,
                              void* d_out, int out_size, void* d_ws, size_t ws_size,
                              hipStream_t stream) {
    (void)in_sizes; (void)n_in; (void)out_size;

    static const int wc[22] = {
        262144, 262144,
        1728, 12288, 192, 192,
        1728, 12288, 192, 192,
        24576, 12288, 192, 192,
        24576, 12288, 192, 192,
        16384, 128,
        3072, 24
    };

    WArgs a;
    int off = 0;
    for (int t = 0; t < 22; ++t) {
        a.src[t] = d_in[t + 1];
        a.off[t] = off;
        off += wc[t];
    }
    a.off[22] = off;

    const unsigned long long arena_bytes = 1294400ull;
    const unsigned long long feat_bytes  = 4096ull * 128ull * 4ull;
    const unsigned long long seq_full    = 72ull * 4096ull * 128ull * 2ull;
    const unsigned long long fixed       = arena_bytes + feat_bytes;

    int nc = 32;
    for (int c = 1; c <= 32; c *= 2) {
        if (fixed + seq_full / (unsigned long long)c <= (unsigned long long)ws_size) { nc = c; break; }
    }
    const int bchunk = 4096 / nc;

    unsigned short* arena = (unsigned short*)d_ws;
    float* feat           = (float*)((char*)d_ws + arena_bytes);
    unsigned short* seq   = (unsigned short*)((char*)d_ws + fixed);

    convert_w<<<64, 256, 0, stream>>>(a, arena, (const unsigned short*)d_in[0]);

    const unsigned short* h0f  = arena + a.off[0];
    const unsigned short* h0b  = arena + a.off[1];
    const unsigned short* d1fW = arena + a.off[2];
    const unsigned short* d1fU = arena + a.off[3];
    const unsigned short* d1fbi= arena + a.off[4];
    const unsigned short* d1fbr= arena + a.off[5];
    const unsigned short* d1bW = arena + a.off[6];
    const unsigned short* d1bU = arena + a.off[7];
    const unsigned short* d1bbi= arena + a.off[8];
    const unsigned short* d1bbr= arena + a.off[9];
    const unsigned short* d2fW = arena + a.off[10];
    const unsigned short* d2fU = arena + a.off[11];
    const unsigned short* d2fbi= arena + a.off[12];
    const unsigned short* d2fbr= arena + a.off[13];
    const unsigned short* d2bW = arena + a.off[14];
    const unsigned short* d2bU = arena + a.off[15];
    const unsigned short* d2bbi= arena + a.off[16];
    const unsigned short* d2bbr= arena + a.off[17];
    const unsigned short* dW   = arena + a.off[18];
    const unsigned short* db   = arena + a.off[19];
    const unsigned short* oW   = arena + a.off[20];
    const unsigned short* ob   = arena + a.off[21];

    for (int c = 0; c < nc; ++c) {
        const int cb = c * bchunk;
        gru1_kernel<<<dim3(bchunk / 16, 2), 256, 0, stream>>>(
            d_in[0], cb, bchunk,
            h0f, h0b, d1fW, d1fU, d1fbi, d1fbr, d1bW, d1bU, d1bbi, d1bbr, seq);
        gru2_kernel<<<dim3(bchunk / 16, 2), 256, 0, stream>>>(
            seq, cb, bchunk,
            d2fW, d2fU, d2fbi, d2fbr, d2bW, d2bU, d2bbi, d2bbr, feat);
    }
    head_kernel<<<256, 256, 0, stream>>>(
        feat, dW, db, oW, ob, (float*)d_out);
}